// Round 4
// baseline (5168.590 us; speedup 1.0000x reference)
//
#include <hip/hip_runtime.h>
#include <cstdint>
#include <cstddef>

#define N_NODES 100000
#define N_EDGES 3200000
#define NMASK   20000
#define LN_EPS  1e-5f

typedef float4 f4;

// ---- workspace layout (float offsets) ----
// enc phase: AHN | FLAGS | A1[N,280] | Z2[N,512] (Z2 doubles as h2, LN in-place)
// dec phase overlays the dead A1 region:
//   Am[MASK,512] at OFF_A1; later Zd0[MASK,256] reuses Am's slot (Am dead)
//   Ad0[MASK,536] after Am; later Ad1[MASK,280] reuses Ad0's slot (Ad0 dead)
#define OFF_AHN   0ull
#define OFF_FLAGS 2400000ull            // N ints
#define OFF_A1    2500000ull            // N*280 = 28,000,000
#define OFF_Z2    30500000ull           // N*512 = 51,200,000 ; ws end = 81.7M floats (327MB)
#define OFF_AM    2500000ull            // MASK*512 = 10,240,000
#define OFF_ZD0   2500000ull            // MASK*256 (after Am dead)
#define OFF_AD0   12740000ull           // MASK*536 = 10,720,000
#define OFF_AD1   12740000ull           // MASK*280 (after Ad0 dead)

__global__ __launch_bounds__(256) void k_scatter_flags(const int* __restrict__ mask,
                                                       int* __restrict__ flags) {
  int i = blockIdx.x * 256 + threadIdx.x;
  if (i < NMASK) flags[mask[i]] = 1;
}

// one thread per edge: build 24-float message, atomically add into ah[dst].
// unsafeAtomicAdd -> global_atomic_add_f32 (HW atomic at L2). Plain atomicAdd
// on float compiles to a CAS loop without -munsafe-fp-atomics, which would be
// catastrophic at 76.8M atomics with 32-way same-address contention.
__global__ __launch_bounds__(256) void k_edge_agg(
    const float* __restrict__ x, const float* __restrict__ dist,
    const float* __restrict__ ang, const float* __restrict__ feat,
    const float* __restrict__ disc, const int* __restrict__ src,
    const int* __restrict__ dst, float* __restrict__ ah) {
  int e = blockIdx.x * 256 + threadIdx.x;
  if (e >= N_EDGES) return;
  int s = src[e], d = dst[e];
  float m[24];
  const float2* xp = reinterpret_cast<const float2*>(x + (size_t)s * 10);
  #pragma unroll
  for (int j = 0; j < 5; ++j) {
    float2 v = xp[j];
    m[2 * j] = v.x; m[2 * j + 1] = v.y;
  }
  m[10] = dist[e];
  m[11] = ang[e];
  f4 f0 = *reinterpret_cast<const f4*>(feat + (size_t)e * 8);
  f4 f1 = *reinterpret_cast<const f4*>(feat + (size_t)e * 8 + 4);
  m[12] = f0.x; m[13] = f0.y; m[14] = f0.z; m[15] = f0.w;
  m[16] = f1.x; m[17] = f1.y; m[18] = f1.z; m[19] = f1.w;
  f4 dv = *reinterpret_cast<const f4*>(disc + (size_t)e * 4);
  m[20] = dv.x; m[21] = dv.y; m[22] = dv.z; m[23] = dv.w;
  float* b = ah + (size_t)d * 24;
  #pragma unroll
  for (int j = 0; j < 24; ++j) unsafeAtomicAdd(b + j, m[j]);
}

__global__ __launch_bounds__(256) void k_scale_ahn(float* __restrict__ ahn,
                                                   const float* __restrict__ norm) {
  int i = blockIdx.x * 256 + threadIdx.x;
  if (i < N_NODES * 24) ahn[i] *= norm[i / 24];
}

// enc0: in34 = [masked_x(10) | ahn(24)] -> Linear(34->256) -> LN -> ReLU -> A1 cols 0..255
// 8 rows per block iteration; W row hoisted to 34 regs per thread (thread == out channel)
__global__ __launch_bounds__(256) void k_enc0(
    const float* __restrict__ x, const float* __restrict__ ahn,
    const int* __restrict__ flags, const float* __restrict__ token,
    const float* __restrict__ W, const float* __restrict__ bias,
    const float* __restrict__ g, const float* __restrict__ beta,
    float* __restrict__ A1) {
  __shared__ float in34[8][34];
  __shared__ float zsh[8][257];
  __shared__ float mu_s[8], rs_s[8];
  int t = threadIdx.x;
  float wreg[34];
  #pragma unroll
  for (int j = 0; j < 34; ++j) wreg[j] = W[t * 34 + j];
  float bb = bias[t], gg = g[t], be = beta[t];
  for (int r0 = blockIdx.x * 8; r0 < N_NODES; r0 += gridDim.x * 8) {
    __syncthreads();
    for (int idx = t; idx < 8 * 34; idx += 256) {
      int r = idx / 34, j = idx % 34;
      int row = r0 + r;
      float v = 0.f;
      if (row < N_NODES) {
        if (j < 10) v = flags[row] ? token[j] : x[(size_t)row * 10 + j];
        else        v = ahn[(size_t)row * 24 + j - 10];
      }
      in34[r][j] = v;
    }
    __syncthreads();
    float acc[8];
    #pragma unroll
    for (int r = 0; r < 8; ++r) acc[r] = bb;
    #pragma unroll 2
    for (int j = 0; j < 34; ++j) {
      float w = wreg[j];
      #pragma unroll
      for (int r = 0; r < 8; ++r) acc[r] += w * in34[r][j];
    }
    #pragma unroll
    for (int r = 0; r < 8; ++r) zsh[r][t] = acc[r];
    __syncthreads();
    {
      int r = t >> 5, l = t & 31;
      float s = 0.f, sq = 0.f;
      #pragma unroll
      for (int i = 0; i < 8; ++i) { float v = zsh[r][l + 32 * i]; s += v; sq += v * v; }
      #pragma unroll
      for (int mm = 16; mm >= 1; mm >>= 1) { s += __shfl_xor(s, mm, 32); sq += __shfl_xor(sq, mm, 32); }
      if (l == 0) {
        float mu = s * (1.f / 256.f);
        float var = sq * (1.f / 256.f) - mu * mu;
        mu_s[r] = mu;
        rs_s[r] = rsqrtf(var + LN_EPS);
      }
    }
    __syncthreads();
    #pragma unroll
    for (int r = 0; r < 8; ++r) {
      int row = r0 + r;
      if (row < N_NODES) {
        float v = (zsh[r][t] - mu_s[r]) * rs_s[r] * gg + be;
        A1[(size_t)row * 280 + t] = fmaxf(v, 0.f);
      }
    }
  }
}

__global__ __launch_bounds__(256) void k_fill_ahn_full(const float* __restrict__ ahn,
                                                       float* __restrict__ A1) {
  int i = blockIdx.x * 256 + threadIdx.x;
  if (i < N_NODES * 24) {
    int r = i / 24, j = i % 24;
    A1[(size_t)r * 280 + 256 + j] = ahn[i];
  }
}

// C[M,Nn] = A[M,K](lda) * W[Nn,K]^T + bias ; 128x128 tile, BK=8, 8x8 per thread
__global__ __launch_bounds__(256) void k_gemm(
    const float* __restrict__ A, int lda,
    const float* __restrict__ W, int K,
    const float* __restrict__ bias,
    float* __restrict__ C, int ldc, int M) {
  __shared__ float As[8][132];
  __shared__ float Bs[8][132];
  int t = threadIdx.x;
  int bm = blockIdx.x * 128, bn = blockIdx.y * 128;
  int lr = t >> 1;
  int lk = (t & 1) * 4;
  int tr = (t >> 4) * 8;
  int tc = (t & 15) * 8;
  float acc[8][8] = {};
  for (int k0 = 0; k0 < K; k0 += 8) {
    f4 av = make_float4(0.f, 0.f, 0.f, 0.f);
    int ar = bm + lr;
    if (ar < M) av = *reinterpret_cast<const f4*>(A + (size_t)ar * lda + k0 + lk);
    f4 bv = *reinterpret_cast<const f4*>(W + (size_t)(bn + lr) * K + k0 + lk);
    __syncthreads();
    As[lk + 0][lr] = av.x; As[lk + 1][lr] = av.y; As[lk + 2][lr] = av.z; As[lk + 3][lr] = av.w;
    Bs[lk + 0][lr] = bv.x; Bs[lk + 1][lr] = bv.y; Bs[lk + 2][lr] = bv.z; Bs[lk + 3][lr] = bv.w;
    __syncthreads();
    #pragma unroll
    for (int k = 0; k < 8; ++k) {
      float a[8], b[8];
      *reinterpret_cast<f4*>(a)     = *reinterpret_cast<const f4*>(&As[k][tr]);
      *reinterpret_cast<f4*>(a + 4) = *reinterpret_cast<const f4*>(&As[k][tr + 4]);
      *reinterpret_cast<f4*>(b)     = *reinterpret_cast<const f4*>(&Bs[k][tc]);
      *reinterpret_cast<f4*>(b + 4) = *reinterpret_cast<const f4*>(&Bs[k][tc + 4]);
      #pragma unroll
      for (int i = 0; i < 8; ++i)
        #pragma unroll
        for (int j = 0; j < 8; ++j)
          acc[i][j] += a[i] * b[j];
    }
  }
  float breg[8];
  #pragma unroll
  for (int j = 0; j < 8; ++j) breg[j] = bias ? bias[bn + tc + j] : 0.f;
  #pragma unroll
  for (int i = 0; i < 8; ++i) {
    int row = bm + tr + i;
    if (row >= M) break;
    float o[8];
    #pragma unroll
    for (int j = 0; j < 8; ++j) o[j] = acc[i][j] + breg[j];
    f4* cp = reinterpret_cast<f4*>(C + (size_t)row * ldc + bn + tc);
    cp[0] = make_float4(o[0], o[1], o[2], o[3]);
    cp[1] = make_float4(o[4], o[5], o[6], o[7]);
  }
}

// LayerNorm + ReLU, one wave per row (D = 256 or 512), supports in-place
__global__ __launch_bounds__(256) void k_ln_relu(
    const float* __restrict__ Z, int ldi,
    float* __restrict__ O, int ldo,
    const float* __restrict__ g, const float* __restrict__ beta,
    int rows, int D) {
  int w = threadIdx.x >> 6;
  int l = threadIdx.x & 63;
  int row = blockIdx.x * 4 + w;
  if (row >= rows) return;
  const float* z = Z + (size_t)row * ldi;
  float vals[8];
  int epl = D >> 6;
  float s = 0.f, sq = 0.f;
  for (int j = 0; j < epl; ++j) {
    float v = z[l + 64 * j];
    vals[j] = v; s += v; sq += v * v;
  }
  #pragma unroll
  for (int mm = 32; mm >= 1; mm >>= 1) { s += __shfl_xor(s, mm); sq += __shfl_xor(sq, mm); }
  float inv = 1.f / (float)D;
  float mu = s * inv;
  float rstd = rsqrtf(sq * inv - mu * mu + LN_EPS);
  float* o = O + (size_t)row * ldo;
  for (int j = 0; j < epl; ++j) {
    int c = l + 64 * j;
    float v = (vals[j] - mu) * rstd * g[c] + beta[c];
    o[c] = fmaxf(v, 0.f);
  }
}

// node-prediction head: z = h2 @ npW^T + b (512->16), LN(16), no relu
// float4 h2 loads (broadcast within 16-lane group); Wl padded [16][516]
// (516 % 32 = 4 -> <=2-way LDS bank aliasing on the 16-lane ds_read_b128)
__global__ __launch_bounds__(256) void k_np(
    const float* __restrict__ h2, const float* __restrict__ W,
    const float* __restrict__ bias, const float* __restrict__ g,
    const float* __restrict__ beta, float* __restrict__ outp) {
  __shared__ float Wl[16][516];
  int t = threadIdx.x;
  for (int idx = t; idx < 16 * 512; idx += 256) Wl[idx >> 9][idx & 511] = W[idx];
  __syncthreads();
  int c = t & 15, rg = t >> 4;
  const f4* wrow = reinterpret_cast<const f4*>(&Wl[c][0]);
  for (int base = blockIdx.x * 16; base < N_NODES; base += gridDim.x * 16) {
    int row = base + rg;
    const f4* h = reinterpret_cast<const f4*>(h2 + (size_t)row * 512);
    float acc = 0.f;
    #pragma unroll 4
    for (int k4 = 0; k4 < 128; ++k4) {
      f4 hv = h[k4];
      f4 wv = wrow[k4];
      acc += hv.x * wv.x + hv.y * wv.y + hv.z * wv.z + hv.w * wv.w;
    }
    acc += bias[c];
    float s = acc, sq = acc * acc;
    #pragma unroll
    for (int mm = 8; mm >= 1; mm >>= 1) { s += __shfl_xor(s, mm, 16); sq += __shfl_xor(sq, mm, 16); }
    float mu = s * (1.f / 16.f);
    float rstd = rsqrtf(sq * (1.f / 16.f) - mu * mu + LN_EPS);
    outp[(size_t)row * 16 + c] = (acc - mu) * rstd * g[c] + beta[c];
  }
}

__global__ __launch_bounds__(256) void k_gather_h2(
    const float* __restrict__ h2, const int* __restrict__ mask,
    float* __restrict__ Am) {
  int i = blockIdx.x * 256 + threadIdx.x;
  if (i < NMASK * 128) {
    int r = i >> 7, c4 = i & 127;
    int node = mask[r];
    reinterpret_cast<f4*>(Am)[(size_t)r * 128 + c4] =
        reinterpret_cast<const f4*>(h2)[(size_t)node * 128 + c4];
  }
}

__global__ __launch_bounds__(256) void k_fill_ahn_mask(
    const float* __restrict__ ahn, const int* __restrict__ mask,
    float* __restrict__ Ad, int ld) {
  int i = blockIdx.x * 256 + threadIdx.x;
  if (i < NMASK * 24) {
    int r = i / 24, j = i % 24;
    Ad[(size_t)r * ld + (ld - 24) + j] = ahn[(size_t)mask[r] * 24 + j];
  }
}

// dec1: (280 -> 10) + LN + ReLU, one wave per row, writes x_pred
__global__ __launch_bounds__(256) void k_dec1(
    const float* __restrict__ Ad1, const float* __restrict__ W,
    const float* __restrict__ bias, const float* __restrict__ g,
    const float* __restrict__ beta, float* __restrict__ outp) {
  __shared__ float Wl[10][284];
  int t = threadIdx.x;
  for (int idx = t; idx < 10 * 280; idx += 256) Wl[idx / 280][idx % 280] = W[idx];
  __syncthreads();
  int w = t >> 6, l = t & 63;
  float b0[10], g0[10], be0[10];
  #pragma unroll
  for (int c = 0; c < 10; ++c) { b0[c] = bias[c]; g0[c] = g[c]; be0[c] = beta[c]; }
  for (int base = blockIdx.x * 4; base < NMASK; base += gridDim.x * 4) {
    int row = base + w;
    float acc[10];
    #pragma unroll
    for (int c = 0; c < 10; ++c) acc[c] = 0.f;
    {
      const float* a = Ad1 + (size_t)row * 280;
      for (int k = l; k < 280; k += 64) {
        float av = a[k];
        #pragma unroll
        for (int c = 0; c < 10; ++c) acc[c] += av * Wl[c][k];
      }
    }
    #pragma unroll
    for (int c = 0; c < 10; ++c)
      #pragma unroll
      for (int mm = 32; mm >= 1; mm >>= 1) acc[c] += __shfl_xor(acc[c], mm);
    float z[10], s = 0.f;
    #pragma unroll
    for (int c = 0; c < 10; ++c) { z[c] = acc[c] + b0[c]; s += z[c]; }
    float mu = s * 0.1f, sq = 0.f;
    #pragma unroll
    for (int c = 0; c < 10; ++c) { float d = z[c] - mu; sq += d * d; }
    float rstd = rsqrtf(sq * 0.1f + LN_EPS);
    if (l < 10)
      outp[(size_t)row * 10 + l] = fmaxf((z[l] - mu) * rstd * g0[l] + be0[l], 0.f);
  }
}

__global__ __launch_bounds__(256) void k_xtrue(const float* __restrict__ x,
                                               const int* __restrict__ mask,
                                               float* __restrict__ outp) {
  int i = blockIdx.x * 256 + threadIdx.x;
  if (i < NMASK * 10) {
    int r = i / 10, j = i % 10;
    outp[i] = x[(size_t)mask[r] * 10 + j];
  }
}

extern "C" void kernel_launch(void* const* d_in, const int* in_sizes, int n_in,
                              void* d_out, int out_size, void* d_ws, size_t ws_size,
                              hipStream_t stream) {
  (void)in_sizes; (void)n_in; (void)out_size; (void)ws_size;
  const float* x     = (const float*)d_in[0];
  const float* dist  = (const float*)d_in[1];
  const float* ang   = (const float*)d_in[2];
  const float* feat  = (const float*)d_in[3];
  const float* disc  = (const float*)d_in[4];
  const float* norm  = (const float*)d_in[5];
  const int*   src   = (const int*)d_in[6];
  const int*   dst   = (const int*)d_in[7];
  const int*   maskn = (const int*)d_in[8];
  const float* token = (const float*)d_in[9];
  const float* e0W = (const float*)d_in[10]; const float* e0b  = (const float*)d_in[11];
  const float* e1W = (const float*)d_in[12]; const float* e1b  = (const float*)d_in[13];
  const float* d0W = (const float*)d_in[14]; const float* d0b  = (const float*)d_in[15];
  const float* d1W = (const float*)d_in[16]; const float* d1b  = (const float*)d_in[17];
  const float* e0g = (const float*)d_in[18]; const float* e0be = (const float*)d_in[19];
  const float* e1g = (const float*)d_in[20]; const float* e1be = (const float*)d_in[21];
  const float* dc0g = (const float*)d_in[22]; const float* dc0be = (const float*)d_in[23];
  const float* dc1g = (const float*)d_in[24]; const float* dc1be = (const float*)d_in[25];
  const float* e2dW = (const float*)d_in[26];
  const float* npW  = (const float*)d_in[27]; const float* npb = (const float*)d_in[28];
  const float* npg  = (const float*)d_in[29]; const float* npbe = (const float*)d_in[30];

  float* ws    = (float*)d_ws;
  float* ahn   = ws + OFF_AHN;
  int*   flags = (int*)(ws + OFF_FLAGS);
  float* A1    = ws + OFF_A1;
  float* Z2    = ws + OFF_Z2;   // also h2 (LN done in place)
  float* Am    = ws + OFF_AM;
  float* Ad0   = ws + OFF_AD0;
  float* Zd0   = ws + OFF_ZD0;
  float* Ad1   = ws + OFF_AD1;

  float* out        = (float*)d_out;
  float* out_xpred  = out;
  float* out_xtrue  = out + (size_t)NMASK * 10;
  float* out_scores = out + (size_t)NMASK * 20;

  // zero ah accumulator + mask flags in one memset
  hipMemsetAsync(ws, 0, (size_t)(N_NODES * 24 + N_NODES) * sizeof(float), stream);
  k_scatter_flags<<<(NMASK + 255) / 256, 256, 0, stream>>>(maskn, flags);
  k_edge_agg<<<(N_EDGES + 255) / 256, 256, 0, stream>>>(x, dist, ang, feat, disc, src, dst, ahn);
  k_scale_ahn<<<(N_NODES * 24 + 255) / 256, 256, 0, stream>>>(ahn, norm);
  k_enc0<<<2048, 256, 0, stream>>>(x, ahn, flags, token, e0W, e0b, e0g, e0be, A1);
  k_fill_ahn_full<<<(N_NODES * 24 + 255) / 256, 256, 0, stream>>>(ahn, A1);
  {
    dim3 g1((N_NODES + 127) / 128, 512 / 128);
    k_gemm<<<g1, 256, 0, stream>>>(A1, 280, e1W, 280, e1b, Z2, 512, N_NODES);
  }
  k_ln_relu<<<(N_NODES + 3) / 4, 256, 0, stream>>>(Z2, 512, Z2, 512, e1g, e1be, N_NODES, 512);
  k_np<<<2048, 256, 0, stream>>>(Z2, npW, npb, npg, npbe, out_scores);
  k_gather_h2<<<(NMASK * 128 + 255) / 256, 256, 0, stream>>>(Z2, maskn, Am);
  {
    dim3 g2((NMASK + 127) / 128, 512 / 128);
    k_gemm<<<g2, 256, 0, stream>>>(Am, 512, e2dW, 512, nullptr, Ad0, 536, NMASK);
  }
  k_fill_ahn_mask<<<(NMASK * 24 + 255) / 256, 256, 0, stream>>>(ahn, maskn, Ad0, 536);
  {
    dim3 g3((NMASK + 127) / 128, 256 / 128);
    k_gemm<<<g3, 256, 0, stream>>>(Ad0, 536, d0W, 536, d0b, Zd0, 256, NMASK);
  }
  k_ln_relu<<<(NMASK + 3) / 4, 256, 0, stream>>>(Zd0, 256, Ad1, 280, dc0g, dc0be, NMASK, 256);
  k_fill_ahn_mask<<<(NMASK * 24 + 255) / 256, 256, 0, stream>>>(ahn, maskn, Ad1, 280);
  k_dec1<<<1250, 256, 0, stream>>>(Ad1, d1W, d1b, dc1g, dc1be, out_xpred);
  k_xtrue<<<(NMASK * 10 + 255) / 256, 256, 0, stream>>>(x, maskn, out_xtrue);
}

// Round 6
// 2023.090 us; speedup vs baseline: 2.5548x; 2.5548x over previous
//
#include <hip/hip_runtime.h>
#include <cstdint>
#include <cstddef>

#define N_NODES 100000
#define N_EDGES 3200000
#define NMASK   20000
#define LN_EPS  1e-5f
#define NSCAN_BLOCKS 391   // ceil(N_NODES/256)

typedef float4 f4;

// ---- workspace layout (float offsets) ----
// enc phase: AHN | FLAGS | A1[N,280] | Z2[N,512] (Z2 doubles as h2, LN in-place)
// CSR scratch (perm/deg/start/cursor/bsum/boff) overlays the A1 region: it is
// dead before k_enc0 writes A1. dec phase overlays A1 likewise (Am->Zd0,
// Ad0->Ad1) -- liveness audited.
#define OFF_AHN   0ull
#define OFF_FLAGS 2400000ull            // N ints
#define OFF_A1    2500000ull            // N*280 = 28,000,000
#define OFF_Z2    30500000ull           // N*512 ; ws end = 81.7M floats (327MB)
#define OFF_AM    2500000ull            // MASK*512
#define OFF_ZD0   2500000ull            // MASK*256 (after Am dead)
#define OFF_AD0   12740000ull           // MASK*536
#define OFF_AD1   12740000ull           // MASK*280 (after Ad0 dead)
// CSR overlay (ints), all within [OFF_A1, OFF_A1+3.6M) << 28M region
#define OFF_PERM  (OFF_A1)              // E ints
#define OFF_DEG   (OFF_A1 + 3200000ull) // N ints
#define OFF_START (OFF_A1 + 3300000ull) // N ints
#define OFF_CURS  (OFF_A1 + 3400000ull) // N ints
#define OFF_BSUM  (OFF_A1 + 3500000ull) // 512 ints
#define OFF_BOFF  (OFF_A1 + 3500512ull) // 512 ints

__global__ __launch_bounds__(256) void k_scatter_flags(const int* __restrict__ mask,
                                                       int* __restrict__ flags) {
  int i = blockIdx.x * 256 + threadIdx.x;
  if (i < NMASK) flags[mask[i]] = 1;
}

// ---- CSR build: histogram -> scan -> scatter ----
__global__ __launch_bounds__(256) void k_hist(const int* __restrict__ dst,
                                              int* __restrict__ deg) {
  int e = blockIdx.x * 256 + threadIdx.x;
  if (e < N_EDGES) atomicAdd(&deg[dst[e]], 1);
}

__global__ __launch_bounds__(256) void k_scan_a(const int* __restrict__ deg,
                                                int* __restrict__ start,
                                                int* __restrict__ bsum) {
  __shared__ int s[256];
  int t = threadIdx.x, idx = blockIdx.x * 256 + t;
  int v = (idx < N_NODES) ? deg[idx] : 0;
  s[t] = v;
  __syncthreads();
  #pragma unroll
  for (int off = 1; off < 256; off <<= 1) {
    int tmp = (t >= off) ? s[t - off] : 0;
    __syncthreads();
    s[t] += tmp;
    __syncthreads();
  }
  if (idx < N_NODES) start[idx] = s[t] - v;     // exclusive within block
  if (t == 255) bsum[blockIdx.x] = s[255];      // block total
}

__global__ __launch_bounds__(512) void k_scan_b(const int* __restrict__ bsum,
                                                int* __restrict__ boff) {
  __shared__ int s[512];
  int t = threadIdx.x;
  int v = (t < NSCAN_BLOCKS) ? bsum[t] : 0;
  s[t] = v;
  __syncthreads();
  #pragma unroll
  for (int off = 1; off < 512; off <<= 1) {
    int tmp = (t >= off) ? s[t - off] : 0;
    __syncthreads();
    s[t] += tmp;
    __syncthreads();
  }
  if (t < NSCAN_BLOCKS) boff[t] = s[t] - v;     // exclusive block offsets
}

__global__ __launch_bounds__(256) void k_scan_c(int* __restrict__ start,
                                                const int* __restrict__ boff,
                                                int* __restrict__ cursor) {
  int i = blockIdx.x * 256 + threadIdx.x;
  if (i < N_NODES) {
    int v = start[i] + boff[i >> 8];
    start[i] = v;
    cursor[i] = v;
  }
}

__global__ __launch_bounds__(256) void k_scatter_edges(const int* __restrict__ dst,
                                                       int* __restrict__ cursor,
                                                       int* __restrict__ perm) {
  int e = blockIdx.x * 256 + threadIdx.x;
  if (e < N_EDGES) {
    int d = dst[e];
    int p = atomicAdd(&cursor[d], 1);
    perm[p] = e;
  }
}

// ---- gather-reduce: wave per node, zero float atomics; fuses *norm ----
__global__ __launch_bounds__(256) void k_gather(
    const float* __restrict__ x, const float* __restrict__ dist,
    const float* __restrict__ ang, const float* __restrict__ feat,
    const float* __restrict__ disc, const int* __restrict__ src,
    const int* __restrict__ perm, const int* __restrict__ start,
    const int* __restrict__ deg, const float* __restrict__ norm,
    float* __restrict__ ahn) {
  int w = threadIdx.x >> 6;
  int l = threadIdx.x & 63;
  int n = blockIdx.x * 4 + w;
  if (n >= N_NODES) return;
  int st = start[n], dg = deg[n];
  float acc[24];
  #pragma unroll
  for (int k = 0; k < 24; ++k) acc[k] = 0.f;
  for (int i = l; i < dg; i += 64) {
    int e = perm[st + i];
    int s = src[e];
    const float2* xp = reinterpret_cast<const float2*>(x + (size_t)s * 10);
    #pragma unroll
    for (int j = 0; j < 5; ++j) {
      float2 v = xp[j];
      acc[2 * j]     += v.x;
      acc[2 * j + 1] += v.y;
    }
    acc[10] += dist[e];
    acc[11] += ang[e];
    f4 f0 = *reinterpret_cast<const f4*>(feat + (size_t)e * 8);
    f4 f1 = *reinterpret_cast<const f4*>(feat + (size_t)e * 8 + 4);
    acc[12] += f0.x; acc[13] += f0.y; acc[14] += f0.z; acc[15] += f0.w;
    acc[16] += f1.x; acc[17] += f1.y; acc[18] += f1.z; acc[19] += f1.w;
    f4 dv = *reinterpret_cast<const f4*>(disc + (size_t)e * 4);
    acc[20] += dv.x; acc[21] += dv.y; acc[22] += dv.z; acc[23] += dv.w;
  }
  float out = 0.f;
  #pragma unroll
  for (int k = 0; k < 24; ++k) {
    float s = acc[k];
    #pragma unroll
    for (int mm = 32; mm >= 1; mm >>= 1) s += __shfl_xor(s, mm);
    if (l == k) out = s;
  }
  if (l < 24) ahn[(size_t)n * 24 + l] = out * norm[n];
}

// enc0: in34 = [masked_x(10) | ahn(24)] -> Linear(34->256) -> LN -> ReLU -> A1 cols 0..255
__global__ __launch_bounds__(256) void k_enc0(
    const float* __restrict__ x, const float* __restrict__ ahn,
    const int* __restrict__ flags, const float* __restrict__ token,
    const float* __restrict__ W, const float* __restrict__ bias,
    const float* __restrict__ g, const float* __restrict__ beta,
    float* __restrict__ A1) {
  __shared__ float in34[8][34];
  __shared__ float zsh[8][257];
  __shared__ float mu_s[8], rs_s[8];
  int t = threadIdx.x;
  float wreg[34];
  #pragma unroll
  for (int j = 0; j < 34; ++j) wreg[j] = W[t * 34 + j];
  float bb = bias[t], gg = g[t], be = beta[t];
  for (int r0 = blockIdx.x * 8; r0 < N_NODES; r0 += gridDim.x * 8) {
    __syncthreads();
    for (int idx = t; idx < 8 * 34; idx += 256) {
      int r = idx / 34, j = idx % 34;
      int row = r0 + r;
      float v = 0.f;
      if (row < N_NODES) {
        if (j < 10) v = flags[row] ? token[j] : x[(size_t)row * 10 + j];
        else        v = ahn[(size_t)row * 24 + j - 10];
      }
      in34[r][j] = v;
    }
    __syncthreads();
    float acc[8];
    #pragma unroll
    for (int r = 0; r < 8; ++r) acc[r] = bb;
    #pragma unroll 2
    for (int j = 0; j < 34; ++j) {
      float w = wreg[j];
      #pragma unroll
      for (int r = 0; r < 8; ++r) acc[r] += w * in34[r][j];
    }
    #pragma unroll
    for (int r = 0; r < 8; ++r) zsh[r][t] = acc[r];
    __syncthreads();
    {
      int r = t >> 5, l = t & 31;
      float s = 0.f, sq = 0.f;
      #pragma unroll
      for (int i = 0; i < 8; ++i) { float v = zsh[r][l + 32 * i]; s += v; sq += v * v; }
      #pragma unroll
      for (int mm = 16; mm >= 1; mm >>= 1) { s += __shfl_xor(s, mm, 32); sq += __shfl_xor(sq, mm, 32); }
      if (l == 0) {
        float mu = s * (1.f / 256.f);
        float var = sq * (1.f / 256.f) - mu * mu;
        mu_s[r] = mu;
        rs_s[r] = rsqrtf(var + LN_EPS);
      }
    }
    __syncthreads();
    #pragma unroll
    for (int r = 0; r < 8; ++r) {
      int row = r0 + r;
      if (row < N_NODES) {
        float v = (zsh[r][t] - mu_s[r]) * rs_s[r] * gg + be;
        A1[(size_t)row * 280 + t] = fmaxf(v, 0.f);
      }
    }
  }
}

__global__ __launch_bounds__(256) void k_fill_ahn_full(const float* __restrict__ ahn,
                                                       float* __restrict__ A1) {
  int i = blockIdx.x * 256 + threadIdx.x;
  if (i < N_NODES * 24) {
    int r = i / 24, j = i % 24;
    A1[(size_t)r * 280 + 256 + j] = ahn[i];
  }
}

// C[M,Nn] = A[M,K](lda) * W[Nn,K]^T + bias ; 128x128 tile, BK=8, 8x8 per thread
__global__ __launch_bounds__(256) void k_gemm(
    const float* __restrict__ A, int lda,
    const float* __restrict__ W, int K,
    const float* __restrict__ bias,
    float* __restrict__ C, int ldc, int M) {
  __shared__ float As[8][132];
  __shared__ float Bs[8][132];
  int t = threadIdx.x;
  int bm = blockIdx.x * 128, bn = blockIdx.y * 128;
  int lr = t >> 1;
  int lk = (t & 1) * 4;
  int tr = (t >> 4) * 8;
  int tc = (t & 15) * 8;
  float acc[8][8] = {};
  for (int k0 = 0; k0 < K; k0 += 8) {
    f4 av = make_float4(0.f, 0.f, 0.f, 0.f);
    int ar = bm + lr;
    if (ar < M) av = *reinterpret_cast<const f4*>(A + (size_t)ar * lda + k0 + lk);
    f4 bv = *reinterpret_cast<const f4*>(W + (size_t)(bn + lr) * K + k0 + lk);
    __syncthreads();
    As[lk + 0][lr] = av.x; As[lk + 1][lr] = av.y; As[lk + 2][lr] = av.z; As[lk + 3][lr] = av.w;
    Bs[lk + 0][lr] = bv.x; Bs[lk + 1][lr] = bv.y; Bs[lk + 2][lr] = bv.z; Bs[lk + 3][lr] = bv.w;
    __syncthreads();
    #pragma unroll
    for (int k = 0; k < 8; ++k) {
      float a[8], b[8];
      *reinterpret_cast<f4*>(a)     = *reinterpret_cast<const f4*>(&As[k][tr]);
      *reinterpret_cast<f4*>(a + 4) = *reinterpret_cast<const f4*>(&As[k][tr + 4]);
      *reinterpret_cast<f4*>(b)     = *reinterpret_cast<const f4*>(&Bs[k][tc]);
      *reinterpret_cast<f4*>(b + 4) = *reinterpret_cast<const f4*>(&Bs[k][tc + 4]);
      #pragma unroll
      for (int i = 0; i < 8; ++i)
        #pragma unroll
        for (int j = 0; j < 8; ++j)
          acc[i][j] += a[i] * b[j];
    }
  }
  float breg[8];
  #pragma unroll
  for (int j = 0; j < 8; ++j) breg[j] = bias ? bias[bn + tc + j] : 0.f;
  #pragma unroll
  for (int i = 0; i < 8; ++i) {
    int row = bm + tr + i;
    if (row >= M) break;
    float o[8];
    #pragma unroll
    for (int j = 0; j < 8; ++j) o[j] = acc[i][j] + breg[j];
    f4* cp = reinterpret_cast<f4*>(C + (size_t)row * ldc + bn + tc);
    cp[0] = make_float4(o[0], o[1], o[2], o[3]);
    cp[1] = make_float4(o[4], o[5], o[6], o[7]);
  }
}

// LayerNorm + ReLU, one wave per row (D = 256 or 512), supports in-place
__global__ __launch_bounds__(256) void k_ln_relu(
    const float* __restrict__ Z, int ldi,
    float* __restrict__ O, int ldo,
    const float* __restrict__ g, const float* __restrict__ beta,
    int rows, int D) {
  int w = threadIdx.x >> 6;
  int l = threadIdx.x & 63;
  int row = blockIdx.x * 4 + w;
  if (row >= rows) return;
  const float* z = Z + (size_t)row * ldi;
  float vals[8];
  int epl = D >> 6;
  float s = 0.f, sq = 0.f;
  for (int j = 0; j < epl; ++j) {
    float v = z[l + 64 * j];
    vals[j] = v; s += v; sq += v * v;
  }
  #pragma unroll
  for (int mm = 32; mm >= 1; mm >>= 1) { s += __shfl_xor(s, mm); sq += __shfl_xor(sq, mm); }
  float inv = 1.f / (float)D;
  float mu = s * inv;
  float rstd = rsqrtf(sq * inv - mu * mu + LN_EPS);
  float* o = O + (size_t)row * ldo;
  for (int j = 0; j < epl; ++j) {
    int c = l + 64 * j;
    float v = (vals[j] - mu) * rstd * g[c] + beta[c];
    o[c] = fmaxf(v, 0.f);
  }
}

// node-prediction head: z = h2 @ npW^T + b (512->16), LN(16), no relu
__global__ __launch_bounds__(256) void k_np(
    const float* __restrict__ h2, const float* __restrict__ W,
    const float* __restrict__ bias, const float* __restrict__ g,
    const float* __restrict__ beta, float* __restrict__ outp) {
  __shared__ float Wl[16][516];
  int t = threadIdx.x;
  for (int idx = t; idx < 16 * 512; idx += 256) Wl[idx >> 9][idx & 511] = W[idx];
  __syncthreads();
  int c = t & 15, rg = t >> 4;
  const f4* wrow = reinterpret_cast<const f4*>(&Wl[c][0]);
  for (int base = blockIdx.x * 16; base < N_NODES; base += gridDim.x * 16) {
    int row = base + rg;
    const f4* h = reinterpret_cast<const f4*>(h2 + (size_t)row * 512);
    float acc = 0.f;
    #pragma unroll 4
    for (int k4 = 0; k4 < 128; ++k4) {
      f4 hv = h[k4];
      f4 wv = wrow[k4];
      acc += hv.x * wv.x + hv.y * wv.y + hv.z * wv.z + hv.w * wv.w;
    }
    acc += bias[c];
    float s = acc, sq = acc * acc;
    #pragma unroll
    for (int mm = 8; mm >= 1; mm >>= 1) { s += __shfl_xor(s, mm, 16); sq += __shfl_xor(sq, mm, 16); }
    float mu = s * (1.f / 16.f);
    float rstd = rsqrtf(sq * (1.f / 16.f) - mu * mu + LN_EPS);
    outp[(size_t)row * 16 + c] = (acc - mu) * rstd * g[c] + beta[c];
  }
}

__global__ __launch_bounds__(256) void k_gather_h2(
    const float* __restrict__ h2, const int* __restrict__ mask,
    float* __restrict__ Am) {
  int i = blockIdx.x * 256 + threadIdx.x;
  if (i < NMASK * 128) {
    int r = i >> 7, c4 = i & 127;
    int node = mask[r];
    reinterpret_cast<f4*>(Am)[(size_t)r * 128 + c4] =
        reinterpret_cast<const f4*>(h2)[(size_t)node * 128 + c4];
  }
}

__global__ __launch_bounds__(256) void k_fill_ahn_mask(
    const float* __restrict__ ahn, const int* __restrict__ mask,
    float* __restrict__ Ad, int ld) {
  int i = blockIdx.x * 256 + threadIdx.x;
  if (i < NMASK * 24) {
    int r = i / 24, j = i % 24;
    Ad[(size_t)r * ld + (ld - 24) + j] = ahn[(size_t)mask[r] * 24 + j];
  }
}

// dec1: (280 -> 10) + LN + ReLU, one wave per row, writes x_pred
__global__ __launch_bounds__(256) void k_dec1(
    const float* __restrict__ Ad1, const float* __restrict__ W,
    const float* __restrict__ bias, const float* __restrict__ g,
    const float* __restrict__ beta, float* __restrict__ outp) {
  __shared__ float Wl[10][284];
  int t = threadIdx.x;
  for (int idx = t; idx < 10 * 280; idx += 256) Wl[idx / 280][idx % 280] = W[idx];
  __syncthreads();
  int w = t >> 6, l = t & 63;
  float b0[10], g0[10], be0[10];
  #pragma unroll
  for (int c = 0; c < 10; ++c) { b0[c] = bias[c]; g0[c] = g[c]; be0[c] = beta[c]; }
  for (int base = blockIdx.x * 4; base < NMASK; base += gridDim.x * 4) {
    int row = base + w;
    float acc[10];
    #pragma unroll
    for (int c = 0; c < 10; ++c) acc[c] = 0.f;
    {
      const float* a = Ad1 + (size_t)row * 280;
      for (int k = l; k < 280; k += 64) {
        float av = a[k];
        #pragma unroll
        for (int c = 0; c < 10; ++c) acc[c] += av * Wl[c][k];
      }
    }
    #pragma unroll
    for (int c = 0; c < 10; ++c)
      #pragma unroll
      for (int mm = 32; mm >= 1; mm >>= 1) acc[c] += __shfl_xor(acc[c], mm);
    float z[10], s = 0.f;
    #pragma unroll
    for (int c = 0; c < 10; ++c) { z[c] = acc[c] + b0[c]; s += z[c]; }
    float mu = s * 0.1f, sq = 0.f;
    #pragma unroll
    for (int c = 0; c < 10; ++c) { float d = z[c] - mu; sq += d * d; }
    float rstd = rsqrtf(sq * 0.1f + LN_EPS);
    if (l < 10)
      outp[(size_t)row * 10 + l] = fmaxf((z[l] - mu) * rstd * g0[l] + be0[l], 0.f);
  }
}

__global__ __launch_bounds__(256) void k_xtrue(const float* __restrict__ x,
                                               const int* __restrict__ mask,
                                               float* __restrict__ outp) {
  int i = blockIdx.x * 256 + threadIdx.x;
  if (i < NMASK * 10) {
    int r = i / 10, j = i % 10;
    outp[i] = x[(size_t)mask[r] * 10 + j];
  }
}

extern "C" void kernel_launch(void* const* d_in, const int* in_sizes, int n_in,
                              void* d_out, int out_size, void* d_ws, size_t ws_size,
                              hipStream_t stream) {
  (void)in_sizes; (void)n_in; (void)out_size; (void)ws_size;
  const float* x     = (const float*)d_in[0];
  const float* dist  = (const float*)d_in[1];
  const float* ang   = (const float*)d_in[2];
  const float* feat  = (const float*)d_in[3];
  const float* disc  = (const float*)d_in[4];
  const float* norm  = (const float*)d_in[5];
  const int*   src   = (const int*)d_in[6];
  const int*   dst   = (const int*)d_in[7];
  const int*   maskn = (const int*)d_in[8];
  const float* token = (const float*)d_in[9];
  const float* e0W = (const float*)d_in[10]; const float* e0b  = (const float*)d_in[11];
  const float* e1W = (const float*)d_in[12]; const float* e1b  = (const float*)d_in[13];
  const float* d0W = (const float*)d_in[14]; const float* d0b  = (const float*)d_in[15];
  const float* d1W = (const float*)d_in[16]; const float* d1b  = (const float*)d_in[17];
  const float* e0g = (const float*)d_in[18]; const float* e0be = (const float*)d_in[19];
  const float* e1g = (const float*)d_in[20]; const float* e1be = (const float*)d_in[21];
  const float* dc0g = (const float*)d_in[22]; const float* dc0be = (const float*)d_in[23];
  const float* dc1g = (const float*)d_in[24]; const float* dc1be = (const float*)d_in[25];
  const float* e2dW = (const float*)d_in[26];
  const float* npW  = (const float*)d_in[27]; const float* npb = (const float*)d_in[28];
  const float* npg  = (const float*)d_in[29]; const float* npbe = (const float*)d_in[30];

  float* ws    = (float*)d_ws;
  float* ahn   = ws + OFF_AHN;
  int*   flags = (int*)(ws + OFF_FLAGS);
  float* A1    = ws + OFF_A1;
  float* Z2    = ws + OFF_Z2;   // also h2 (LN done in place)
  float* Am    = ws + OFF_AM;
  float* Ad0   = ws + OFF_AD0;
  float* Zd0   = ws + OFF_ZD0;
  float* Ad1   = ws + OFF_AD1;
  int* perm   = (int*)(ws + OFF_PERM);
  int* deg    = (int*)(ws + OFF_DEG);
  int* startp = (int*)(ws + OFF_START);
  int* cursor = (int*)(ws + OFF_CURS);
  int* bsum   = (int*)(ws + OFF_BSUM);
  int* boff   = (int*)(ws + OFF_BOFF);

  float* out        = (float*)d_out;
  float* out_xpred  = out;
  float* out_xtrue  = out + (size_t)NMASK * 10;
  float* out_scores = out + (size_t)NMASK * 20;

  // zero flags + deg
  hipMemsetAsync(flags, 0, (size_t)N_NODES * sizeof(int), stream);
  hipMemsetAsync(deg, 0, (size_t)N_NODES * sizeof(int), stream);
  k_scatter_flags<<<(NMASK + 255) / 256, 256, 0, stream>>>(maskn, flags);

  // CSR build (all int atomics; no float atomics anywhere)
  k_hist<<<(N_EDGES + 255) / 256, 256, 0, stream>>>(dst, deg);
  k_scan_a<<<NSCAN_BLOCKS, 256, 0, stream>>>(deg, startp, bsum);
  k_scan_b<<<1, 512, 0, stream>>>(bsum, boff);
  k_scan_c<<<NSCAN_BLOCKS, 256, 0, stream>>>(startp, boff, cursor);
  k_scatter_edges<<<(N_EDGES + 255) / 256, 256, 0, stream>>>(dst, cursor, perm);

  // gather-reduce per node, fused * norm
  k_gather<<<(N_NODES + 3) / 4, 256, 0, stream>>>(x, dist, ang, feat, disc, src,
                                                  perm, startp, deg, norm, ahn);

  k_enc0<<<2048, 256, 0, stream>>>(x, ahn, flags, token, e0W, e0b, e0g, e0be, A1);
  k_fill_ahn_full<<<(N_NODES * 24 + 255) / 256, 256, 0, stream>>>(ahn, A1);
  {
    dim3 g1((N_NODES + 127) / 128, 512 / 128);
    k_gemm<<<g1, 256, 0, stream>>>(A1, 280, e1W, 280, e1b, Z2, 512, N_NODES);
  }
  k_ln_relu<<<(N_NODES + 3) / 4, 256, 0, stream>>>(Z2, 512, Z2, 512, e1g, e1be, N_NODES, 512);
  k_np<<<2048, 256, 0, stream>>>(Z2, npW, npb, npg, npbe, out_scores);
  k_gather_h2<<<(NMASK * 128 + 255) / 256, 256, 0, stream>>>(Z2, maskn, Am);
  {
    dim3 g2((NMASK + 127) / 128, 512 / 128);
    k_gemm<<<g2, 256, 0, stream>>>(Am, 512, e2dW, 512, nullptr, Ad0, 536, NMASK);
  }
  k_fill_ahn_mask<<<(NMASK * 24 + 255) / 256, 256, 0, stream>>>(ahn, maskn, Ad0, 536);
  {
    dim3 g3((NMASK + 127) / 128, 256 / 128);
    k_gemm<<<g3, 256, 0, stream>>>(Ad0, 536, d0W, 536, d0b, Zd0, 256, NMASK);
  }
  k_ln_relu<<<(NMASK + 3) / 4, 256, 0, stream>>>(Zd0, 256, Ad1, 280, dc0g, dc0be, NMASK, 256);
  k_fill_ahn_mask<<<(NMASK * 24 + 255) / 256, 256, 0, stream>>>(ahn, maskn, Ad1, 280);
  k_dec1<<<1250, 256, 0, stream>>>(Ad1, d1W, d1b, dc1g, dc1be, out_xpred);
  k_xtrue<<<(NMASK * 10 + 255) / 256, 256, 0, stream>>>(x, maskn, out_xtrue);
}